// Round 9
// baseline (4007.893 us; speedup 1.0000x reference)
//
#include <hip/hip_runtime.h>
#include <hip/hip_fp16.h>

typedef _Float16 f16;
typedef _Float16 f16x8 __attribute__((ext_vector_type(8)));
typedef float    f32x4 __attribute__((ext_vector_type(4)));

#define HID 512
#define FEA 128
#define ROWSTR 129            // inputs row = 128 feat + 1 shock
#define SEQL 512
#define DEN1 64
#define NG 8                  // batch groups (16 rows each)
#define WPG 32                // workgroups per group
#define MB 16                 // batch rows per group
#define GC 16                 // gate columns per wg
#define THREADS 256
#define NFLG 128              // flags per group: one per wave (32 WG x 4 waves)

// workspace (bytes); zeroed every launch via hipMemsetAsync
#define WS_CTR    0                     // 64 u32: final-barrier counters
#define WS_FLG    256                   // NG*128 u32 per-wave step flags (monotonic)
#define WS_HRING  8192                  // 2*NG*MB*HID f16 = 262144 B
#define WS_SM     (WS_HRING + 262144)   // 128 f32 shock means
#define WS_HPART  (WS_SM + 1024)        // NG*WPG*MB f32 head partials
#define WS_END    (WS_HPART + 16384)

#define WAITV0 { asm volatile("s_waitcnt vmcnt(0)" ::: "memory"); __builtin_amdgcn_sched_barrier(0); }

__device__ __forceinline__ void st_h2(void* p, unsigned v) {
    asm volatile("global_store_short %0, %1, off sc0 sc1" :: "v"(p), "v"(v) : "memory");
}
__device__ __forceinline__ unsigned long long ld_u64c(const void* p) {
    unsigned long long r;
    asm volatile("global_load_dwordx2 %0, %1, off sc0 sc1" : "=v"(r) : "v"(p));
    asm volatile("s_waitcnt vmcnt(0)" ::: "memory");
    return r;
}
__device__ __forceinline__ void st_u32c(void* p, unsigned v) {
    asm volatile("global_store_dword %0, %1, off sc0 sc1" :: "v"(p), "v"(v) : "memory");
}
__device__ __forceinline__ unsigned ld_u32c(const void* p) {
    unsigned r;
    asm volatile("global_load_dword %0, %1, off sc0 sc1" : "=v"(r) : "v"(p) : "memory");
    asm volatile("s_waitcnt vmcnt(0)" ::: "memory");
    return r;
}
// reduce barrier: LDS visibility only (VMEM stays in flight across it)
__device__ __forceinline__ void barrier_lgkm() {
    asm volatile("s_waitcnt lgkmcnt(0)" ::: "memory");
    __builtin_amdgcn_sched_barrier(0);
    __builtin_amdgcn_s_barrier();
    __builtin_amdgcn_sched_barrier(0);
    asm volatile("" ::: "memory");
}

__device__ __forceinline__ float sigmoid_f(float x) {
    x = fminf(fmaxf(x, -30.f), 30.f);
    return 1.f / (1.f + __expf(-x));
}
__device__ __forceinline__ float tanh_f(float x) {
    x = fminf(fmaxf(x, -15.f), 15.f);
    float e = __expf(2.f * x);
    return (e - 1.f) / (e + 1.f);
}

__global__ __launch_bounds__(THREADS)
void gru_fused(const float* __restrict__ inp, const float* __restrict__ Wk,
               const float* __restrict__ Rk,  const float* __restrict__ bias,
               const float* __restrict__ W1,  const float* __restrict__ b1,
               const float* __restrict__ gam, const float* __restrict__ bet,
               const float* __restrict__ mmn, const float* __restrict__ mvr,
               const float* __restrict__ W2,  const float* __restrict__ b2p,
               const float* __restrict__ Wsh, float* __restrict__ out,
               char* __restrict__ ws)
{
    __shared__ __align__(16) f16 Bh[512 * 48];   // 49152 B: R gate-col B-frags
    __shared__ __align__(16) f16 Bx[128 * 48];   // 12288 B: Wk gate-col B-frags
    __shared__ float red[4608];                   // 18432 B: 4x768 partials + 2x768 x-stash
    // total LDS 79872 B -> 2 blocks/CU capacity (proven R1-R3/R6 regime)

    const int tid  = threadIdx.x;
    const int g    = blockIdx.x & (NG - 1);
    const int wgk  = blockIdx.x >> 3;
    const int lane = tid & 63;
    const int wave = tid >> 6;
    const int j0   = wgk * GC;

    unsigned* ctr   = (unsigned*)(ws + WS_CTR);
    unsigned* flg   = (unsigned*)(ws + WS_FLG);
    f16*      hring = (f16*)(ws + WS_HRING);
    float*    smw   = (float*)(ws + WS_SM);
    float*    hpart = (float*)(ws + WS_HPART);

    // ---- stage B-fragments ----
    for (int idx = tid; idx < 512 * 48; idx += THREADS) {
        int kk = idx / 48, c = idx - kk * 48;
        int col = (c >> 4) * HID + j0 + (c & 15);
        Bh[((kk >> 3) * 48 + c) * 8 + (kk & 7)] = (f16)Rk[(size_t)kk * 1536 + col];
    }
    for (int idx = tid; idx < 128 * 48; idx += THREADS) {
        int kk = idx / 48, c = idx - kk * 48;
        int col = (c >> 4) * HID + j0 + (c & 15);
        Bx[((kk >> 3) * 48 + c) * 8 + (kk & 7)] = (f16)Wk[(size_t)kk * 1536 + col];
    }

    // ---- shock mean (coherent publish) ----
    if (wgk < MB) {
        int b = g * MB + wgk;
        float a = 0.f;
        for (int t = tid; t < SEQL; t += THREADS)
            a += inp[((size_t)b * SEQL + t) * ROWSTR + FEA];
        red[tid] = a;
        __syncthreads();
        for (int s = THREADS / 2; s > 0; s >>= 1) {
            if (tid < s) red[tid] += red[tid + s];
            __syncthreads();
        }
        if (tid == 0) {
            union { float f; unsigned u; } cv; cv.f = red[0] * (1.f / SEQL);
            st_u32c(smw + b, cv.u);
        }
    }

    // per-thread constants
    const int brow  = tid >> 4;
    const int jcol  = j0 + (tid & 15);
    const int arow  = lane & 15;
    const int ahalf = lane >> 4;
    const int lcol  = j0 + (lane & 15);
    const float bZ3  = bias[lcol] + bias[1536 + lcol];
    const float bR3  = bias[512 + lcol] + bias[1536 + 512 + lcol];
    const float bX3  = bias[1024 + lcol];
    const float bHH3 = bias[1536 + 1024 + lcol];

    float xa[4][8];   // wave3: x floats, ~2 steps ahead

    auto x_window = [&](int t) {   // convert x(t+1), 12 MFMAs, stash, load x(t+2)
        f16x8 afx[4];
        #pragma unroll
        for (int s = 0; s < 4; ++s) {
            f16x8 a;
            #pragma unroll
            for (int q = 0; q < 8; ++q) a[q] = (f16)xa[s][q];
            afx[s] = a;
        }
        f32x4 az = {0,0,0,0}, ar = {0,0,0,0}, ah = {0,0,0,0};
        #pragma unroll
        for (int s = 0; s < 4; ++s) {
            const f16x8* bx = ((const f16x8*)Bx) + (s * 4 + ahalf) * 48 + (lane & 15);
            az = __builtin_amdgcn_mfma_f32_16x16x32_f16(afx[s], bx[0],  az, 0, 0, 0);
            ar = __builtin_amdgcn_mfma_f32_16x16x32_f16(afx[s], bx[16], ar, 0, 0, 0);
            ah = __builtin_amdgcn_mfma_f32_16x16x32_f16(afx[s], bx[32], ah, 0, 0, 0);
        }
        float* xo = red + 3072 + ((t + 1) & 1) * 768;
        #pragma unroll
        for (int i = 0; i < 4; ++i) {
            int rix = (ahalf * 4 + i) * 16 + (lane & 15);
            xo[rix]       = az[i] + bZ3;
            xo[256 + rix] = ar[i] + bR3;
            xo[512 + rix] = ah[i] + bX3;
        }
        int tt = (t + 2 < SEQL) ? t + 2 : SEQL - 1;
        const float* xs = inp + ((size_t)(g * MB + arow) * SEQL + tt) * ROWSTR + ahalf * 8;
        #pragma unroll
        for (int s = 0; s < 4; ++s)
            #pragma unroll
            for (int q = 0; q < 8; ++q)
                xa[s][q] = xs[s * 32 + q];
    };

    __syncthreads();   // staging + shock-mean done

    if (wave == 3) {   // prologue: stash x-proj(0), issue x(1)
        const float* xs = inp + ((size_t)(g * MB + arow) * SEQL + 0) * ROWSTR + ahalf * 8;
        #pragma unroll
        for (int s = 0; s < 4; ++s)
            #pragma unroll
            for (int q = 0; q < 8; ++q)
                xa[s][q] = xs[s * 32 + q];
        x_window(-1);
    }

    float hold = 0.f;  // own h element (h0 = 0)
    const unsigned long long* fp = (const unsigned long long*)(flg + (size_t)g * NFLG) + lane;
    unsigned* myflag = flg + (size_t)g * NFLG + wgk * 4 + wave;

    // simple drain-poll: 2 flags per lane (covers all 128), full vmcnt(0) per attempt
    auto poll_all = [&](unsigned want) {
        for (;;) {
            unsigned long long fv;
            asm volatile("global_load_dwordx2 %0, %1, off sc0 sc1"
                         : "=v"(fv) : "v"(fp) : "memory");
            asm volatile("s_waitcnt vmcnt(0)" ::: "memory");
            __builtin_amdgcn_sched_barrier(0);
            if (__all((int)((unsigned)fv >= want && (unsigned)(fv >> 32) >= want))) break;
        }
    };

    #pragma unroll 1
    for (int t = 0; t < SEQL; ++t) {
        const int cur = t & 1;

        // ---- poll: all 128 group flags >= t (every wave independently); drains
        //      prev flag store + wave3's in-flight x loads as a side effect ----
        poll_all((unsigned)t);

        // ---- h loads + MFMA partials (waves 0-2: k-chunks 5w..5w+4; wave3: chunk 15) ----
        const f16* hb = hring + ((size_t)cur * NG + g) * MB * HID
                              + (size_t)arow * HID + ahalf * 8 + wave * 5 * 32;
        f16x8 af[5];
        if (wave < 3) {
            #pragma unroll
            for (int s = 0; s < 5; ++s)
                asm volatile("global_load_dwordx4 %0, %1, off offset:%c2 sc0 sc1"
                             : "=v"(af[s]) : "v"(hb), "i"(s * 64));
        } else {
            asm volatile("global_load_dwordx4 %0, %1, off sc0 sc1" : "=v"(af[0]) : "v"(hb));
        }
        WAITV0;   // h frags ready

        f32x4 aZ = {0,0,0,0}, aR = {0,0,0,0}, aH = {0,0,0,0};
        if (wave < 3) {
            #pragma unroll
            for (int s = 0; s < 5; ++s) {
                int ks = wave * 5 + s;
                const f16x8* bp = ((const f16x8*)Bh) + (ks * 4 + ahalf) * 48 + (lane & 15);
                aZ = __builtin_amdgcn_mfma_f32_16x16x32_f16(af[s], bp[0],  aZ, 0, 0, 0);
                aR = __builtin_amdgcn_mfma_f32_16x16x32_f16(af[s], bp[16], aR, 0, 0, 0);
                aH = __builtin_amdgcn_mfma_f32_16x16x32_f16(af[s], bp[32], aH, 0, 0, 0);
            }
            #pragma unroll
            for (int i = 0; i < 4; ++i) {
                int rix = (ahalf * 4 + i) * 16 + (lane & 15);
                red[wave * 768 +       rix] = aZ[i];
                red[wave * 768 + 256 + rix] = aR[i];
                red[wave * 768 + 512 + rix] = aH[i];
            }
        } else {
            const f16x8* bp = ((const f16x8*)Bh) + (15 * 4 + ahalf) * 48 + (lane & 15);
            aZ = __builtin_amdgcn_mfma_f32_16x16x32_f16(af[0], bp[0],  aZ, 0, 0, 0);
            aR = __builtin_amdgcn_mfma_f32_16x16x32_f16(af[0], bp[16], aR, 0, 0, 0);
            aH = __builtin_amdgcn_mfma_f32_16x16x32_f16(af[0], bp[32], aH, 0, 0, 0);
            #pragma unroll
            for (int i = 0; i < 4; ++i) {
                int rix = (ahalf * 4 + i) * 16 + (lane & 15);
                red[3 * 768 +       rix] = aZ[i];
                red[3 * 768 + 256 + rix] = aR[i];
                red[3 * 768 + 512 + rix] = aH[i] + bHH3;   // fold recurrent cand bias once
            }
        }
        barrier_lgkm();   // partials + x-stash visible (VMEM not drained)

        // ---- gates: thread owns (brow, jcol) ----
        {
            float zp = red[tid] + red[768 + tid] + red[1536 + tid] + red[2304 + tid];
            float rp = red[256 + tid] + red[1024 + tid] + red[1792 + tid] + red[2560 + tid];
            float hp = red[512 + tid] + red[1280 + tid] + red[2048 + tid] + red[2816 + tid];
            const float* xi = red + 3072 + cur * 768;
            float z = sigmoid_f(zp + xi[tid]);
            float r = sigmoid_f(rp + xi[256 + tid]);
            float hc = tanh_f(xi[512 + tid] + r * hp);
            float hnew = z * hold + (1.f - z) * hc;
            f16 h16 = (f16)hnew;
            hold = (float)h16;
            union { f16 h; unsigned short u; } cv; cv.h = h16;
            st_h2(hring + (((size_t)(cur ^ 1) * NG + g) * MB + brow) * HID + jcol,
                  (unsigned)cv.u);
        }
        WAITV0;                                              // own wave's h-store drained
        if (lane == 0) st_u32c(myflag, (unsigned)(t + 1));   // per-wave flag

        if (wave == 3 && t + 1 < SEQL)
            x_window(t);     // x(t+2) loads left in flight; drained by next poll
    }

    poll_all((unsigned)SEQL);   // h_512 visible everywhere
    __syncthreads();

    // ---- head: state=(h + shock_mean*W_shock); relu(state@W1+b1); BN; @W2+b2 ----
    const f16* hf = hring + ((size_t)g * MB + brow) * HID;   // slot 0 holds h_512
    const int sub = tid & 15;
    const int c0 = wgk * 2;
    float p0 = 0.f, p1 = 0.f, w0 = 0.f, w1 = 0.f;
    for (int c8 = 0; c8 < 8; ++c8) {
        union { unsigned long long u; f16 h[4]; } x;
        x.u = ld_u64c(hf + sub * 32 + c8 * 4);
        #pragma unroll
        for (int e = 0; e < 4; ++e) {
            int k = sub * 32 + c8 * 4 + e;
            float hv = (float)x.h[e];
            float a0 = W1[(size_t)k * DEN1 + c0];
            float a1 = W1[(size_t)k * DEN1 + c0 + 1];
            p0 += hv * a0; p1 += hv * a1; w0 += a0; w1 += a1;
        }
    }
    __syncthreads();
    red[tid] = p0; red[256 + tid] = w0; red[512 + tid] = p1; red[768 + tid] = w1;
    __syncthreads();
    if (tid < 32) {
        int b = tid >> 1, cc = tid & 1;
        int c = c0 + cc;
        float dot = 0.f, wsum = 0.f;
        for (int i = 0; i < 16; ++i) {
            dot  += red[cc * 512 + b * 16 + i];
            wsum += red[cc * 512 + 256 + b * 16 + i];
        }
        union { unsigned u; float f; } sm; sm.u = ld_u32c(smw + g * MB + b);
        float sW = sm.f * Wsh[0];
        float d = dot + sW * wsum + b1[c];
        d = fmaxf(d, 0.f);
        d = (d - mmn[c]) * rsqrtf(mvr[c] + 0.001f) * gam[c] + bet[c];
        red[1024 + tid] = d * W2[c];
    }
    __syncthreads();
    if (tid < MB)
        hpart[((size_t)g * WPG + wgk) * MB + tid] = red[1024 + tid * 2] + red[1024 + tid * 2 + 1];
    __syncthreads();
    if (tid == 0) {
        __builtin_amdgcn_fence(__ATOMIC_RELEASE, "agent");
        unsigned* c9 = ctr + g;
        unsigned old = __hip_atomic_fetch_add(c9, 1u, __ATOMIC_RELAXED, __HIP_MEMORY_SCOPE_AGENT);
        if (old != WPG - 1)
            while (__hip_atomic_load(c9, __ATOMIC_RELAXED, __HIP_MEMORY_SCOPE_AGENT) < WPG) {}
        __builtin_amdgcn_fence(__ATOMIC_ACQUIRE, "agent");
    }
    __syncthreads();
    if (wgk == 0 && tid < MB) {
        float o = b2p[0];
        for (int k = 0; k < WPG; ++k)
            o += hpart[((size_t)g * WPG + k) * MB + tid];
        out[g * MB + tid] = o;
    }
}

extern "C" void kernel_launch(void* const* d_in, const int* in_sizes, int n_in,
                              void* d_out, int out_size, void* d_ws, size_t ws_size,
                              hipStream_t stream) {
    (void)in_sizes; (void)n_in; (void)out_size; (void)ws_size;
    const float* inp  = (const float*)d_in[0];
    const float* Wk   = (const float*)d_in[1];
    const float* Rk   = (const float*)d_in[2];
    const float* bias = (const float*)d_in[3];
    const float* W1   = (const float*)d_in[4];
    const float* b1   = (const float*)d_in[5];
    const float* gam  = (const float*)d_in[6];
    const float* bet  = (const float*)d_in[7];
    const float* mmn  = (const float*)d_in[8];
    const float* mvr  = (const float*)d_in[9];
    const float* W2   = (const float*)d_in[10];
    const float* b2p  = (const float*)d_in[11];
    const float* Wsh  = (const float*)d_in[12];

    hipMemsetAsync(d_ws, 0, WS_END, stream);   // flags/counters + h0 = 0, every launch
    hipLaunchKernelGGL(gru_fused, dim3(NG * WPG), dim3(THREADS), 0, stream,
                       inp, Wk, Rk, bias, W1, b1, gam, bet, mmn, mvr, W2, b2p, Wsh,
                       (float*)d_out, (char*)d_ws);
}

// Round 10
// 1695.539 us; speedup vs baseline: 2.3638x; 2.3638x over previous
//
#include <hip/hip_runtime.h>
#include <hip/hip_fp16.h>

typedef _Float16 f16;
typedef _Float16 f16x8 __attribute__((ext_vector_type(8)));
typedef float    f32x4 __attribute__((ext_vector_type(4)));

#define HID 512
#define FEA 128
#define ROWSTR 129            // inputs row = 128 feat + 1 shock
#define SEQL 512
#define DEN1 64
#define NG 8                  // batch groups (16 rows each)
#define WPG 16                // workgroups per group (each owns 32 h-cols)
#define MB 16                 // batch rows per group
#define HCOL 32               // h-columns per WG
#define THREADS 256

// workspace (bytes); zeroed every launch via hipMemsetAsync
#define WS_CTR    0                     // 64 u32: final-barrier counters
#define WS_FLG    256                   // NG*16 u32 per-WG step flags (monotonic)
#define WS_HRING  4096                  // 2*NG*MB*HID f16 = 262144 B
#define WS_SM     (WS_HRING + 262144)   // 128 f32 shock means
#define WS_HPART  (WS_SM + 1024)        // NG*WPG*MB f32 head partials
#define WS_END    (WS_HPART + 8192)

#define MFMA16(a,b,c) __builtin_amdgcn_mfma_f32_16x16x32_f16((a),(b),(c),0,0,0)
#define WAITV0 { asm volatile("s_waitcnt vmcnt(0)" ::: "memory"); __builtin_amdgcn_sched_barrier(0); }

__device__ __forceinline__ unsigned long long ld_u64c(const void* p) {
    unsigned long long r;
    asm volatile("global_load_dwordx2 %0, %1, off sc0 sc1" : "=v"(r) : "v"(p));
    asm volatile("s_waitcnt vmcnt(0)" ::: "memory");
    return r;
}
__device__ __forceinline__ void st_u32c(void* p, unsigned v) {
    asm volatile("global_store_dword %0, %1, off sc0 sc1" :: "v"(p), "v"(v) : "memory");
}
__device__ __forceinline__ unsigned ld_u32c(const void* p) {
    unsigned r;
    asm volatile("global_load_dword %0, %1, off sc0 sc1" : "=v"(r) : "v"(p) : "memory");
    asm volatile("s_waitcnt vmcnt(0)" ::: "memory");
    return r;
}
__device__ __forceinline__ void barrier_lgkm() {
    asm volatile("s_waitcnt lgkmcnt(0)" ::: "memory");
    __builtin_amdgcn_sched_barrier(0);
    __builtin_amdgcn_s_barrier();
    __builtin_amdgcn_sched_barrier(0);
    asm volatile("" ::: "memory");
}

__device__ __forceinline__ float sigmoid_f(float x) {
    x = fminf(fmaxf(x, -30.f), 30.f);
    return 1.f / (1.f + __expf(-x));
}
__device__ __forceinline__ float tanh_f(float x) {
    x = fminf(fmaxf(x, -15.f), 15.f);
    float e = __expf(2.f * x);
    return (e - 1.f) / (e + 1.f);
}

__global__ __launch_bounds__(THREADS)
void gru_fused(const float* __restrict__ inp, const float* __restrict__ Wk,
               const float* __restrict__ Rk,  const float* __restrict__ bias,
               const float* __restrict__ W1,  const float* __restrict__ b1,
               const float* __restrict__ gam, const float* __restrict__ bet,
               const float* __restrict__ mmn, const float* __restrict__ mvr,
               const float* __restrict__ W2,  const float* __restrict__ b2p,
               const float* __restrict__ Wsh, float* __restrict__ out,
               char* __restrict__ ws)
{
    __shared__ __align__(16) f16 Bh[512 * 96];   // 98304 B: R slice (96 gate-cols) B-frags
    __shared__ float red[8192];                   // 32768 B: 4 waves x 8 tiles x 256
    // 131072 B total -> 1 block/CU; grid=128 <= 256 CUs: all blocks resident by capacity

    const int tid  = threadIdx.x;
    const int g    = blockIdx.x & (NG - 1);
    const int wgk  = blockIdx.x >> 3;          // 0..15
    const int lane = tid & 63;
    const int wave = tid >> 6;
    const int j0   = wgk * HCOL;               // first h-col owned
    const int arow = lane & 15, ahalf = lane >> 4;

    unsigned* ctr   = (unsigned*)(ws + WS_CTR);
    unsigned* flg   = (unsigned*)(ws + WS_FLG);
    f16*      hring = (f16*)(ws + WS_HRING);
    float*    smw   = (float*)(ws + WS_SM);
    float*    hpart = (float*)(ws + WS_HPART);

    // ---- stage Bh: 96 cols = z|r|h x 32, col c -> global (c>>5)*512 + j0 + (c&31) ----
    for (int idx = tid; idx < 512 * 96; idx += THREADS) {
        int kk = idx / 96, c = idx - kk * 96;
        int col = (c >> 5) * HID + j0 + (c & 31);
        Bh[((kk >> 3) * 96 + c) * 8 + (kk & 7)] = (f16)Rk[(size_t)kk * 1536 + col];
    }
    // ---- x B-frags in registers: this wave's x-kstep (k = wave*32 + ...) ----
    f16x8 bxr[6];
    #pragma unroll
    for (int tile = 0; tile < 6; ++tile) {
        int col = (tile >> 1) * HID + j0 + (tile & 1) * 16 + (lane & 15);
        f16x8 v;
        #pragma unroll
        for (int e = 0; e < 8; ++e)
            v[e] = (f16)Wk[(size_t)(wave * 32 + ahalf * 8 + e) * 1536 + col];
        bxr[tile] = v;
    }

    // ---- shock mean: WG wgk handles batch row g*16+wgk ----
    {
        int b = g * MB + wgk;
        float a = 0.f;
        for (int t = tid; t < SEQL; t += THREADS)
            a += inp[((size_t)b * SEQL + t) * ROWSTR + FEA];
        red[tid] = a;
        __syncthreads();
        for (int s = THREADS / 2; s > 0; s >>= 1) {
            if (tid < s) red[tid] += red[tid + s];
            __syncthreads();
        }
        if (tid == 0) {
            union { float f; unsigned u; } cv; cv.f = red[0] * (1.f / SEQL);
            st_u32c(smw + b, cv.u);
        }
    }

    // per-thread gate constants: thread (brow=tid>>4) owns cols j0 + cp*2 + {0,1}
    const int brow = tid >> 4;
    const int cp   = tid & 15;
    float bZs[2], bRs[2], bXs[2], bHs[2];
    #pragma unroll
    for (int s = 0; s < 2; ++s) {
        int jc = j0 + cp * 2 + s;
        bZs[s] = bias[jc] + bias[1536 + jc];
        bRs[s] = bias[512 + jc] + bias[1536 + 512 + jc];
        bXs[s] = bias[1024 + jc];
        bHs[s] = bias[1536 + 1024 + jc];
    }

    __syncthreads();   // Bh + shock-mean done

    float hold[2] = {0.f, 0.f};
    const unsigned* fpoll = flg + g * WPG + wave * 4 + (lane & 3);   // 4 source WGs
    unsigned* myflag = flg + g * WPG + wgk;

    #pragma unroll 1
    for (int t = 0; t < SEQL; ++t) {
        const int cur = t & 1;

        // ---- per-wave poll: 4 source flags >= t (sources own cols [wave*128,+128)) ----
        for (;;) {
            unsigned v;
            asm volatile("global_load_dword %0, %1, off sc0 sc1" : "=v"(v) : "v"(fpoll) : "memory");
            asm volatile("s_waitcnt vmcnt(0)" ::: "memory");
            __builtin_amdgcn_sched_barrier(0);
            if (__all((int)(v >= (unsigned)t))) break;
        }

        // ---- loads: this wave's h k-chunk (coherent) + x quarter (plain) ----
        const f16* hb = hring + ((size_t)cur * NG + g) * MB * HID
                              + (size_t)arow * HID + wave * 128 + ahalf * 8;
        f16x8 af[4];
        asm volatile("global_load_dwordx4 %0, %1, off sc0 sc1"            : "=v"(af[0]) : "v"(hb));
        asm volatile("global_load_dwordx4 %0, %1, off offset:64 sc0 sc1"  : "=v"(af[1]) : "v"(hb));
        asm volatile("global_load_dwordx4 %0, %1, off offset:128 sc0 sc1" : "=v"(af[2]) : "v"(hb));
        asm volatile("global_load_dwordx4 %0, %1, off offset:192 sc0 sc1" : "=v"(af[3]) : "v"(hb));
        const float* xb = inp + ((size_t)(g * MB + arow) * SEQL + t) * ROWSTR
                              + wave * 32 + ahalf * 8;
        f32x4 x0, x1;
        asm volatile("global_load_dwordx4 %0, %1, off"            : "=v"(x0) : "v"(xb));
        asm volatile("global_load_dwordx4 %0, %1, off offset:16"  : "=v"(x1) : "v"(xb));
        WAITV0;
        f16x8 xa;
        #pragma unroll
        for (int e = 0; e < 4; ++e) { xa[e] = (f16)x0[e]; xa[4 + e] = (f16)x1[e]; }

        // ---- 24 h-MFMAs + 6 x-MFMAs; tiles: z0 z1 r0 r1 h0 h1 (+x-cand x0 x1) ----
        f32x4 a0={0,0,0,0},a1={0,0,0,0},a2={0,0,0,0},a3={0,0,0,0},a4={0,0,0,0},a5={0,0,0,0};
        f32x4 ax0={0,0,0,0},ax1={0,0,0,0};
        const f16x8* BF = (const f16x8*)Bh;
        #pragma unroll
        for (int ks = 0; ks < 4; ++ks) {
            const f16x8* bp = BF + ((wave * 4 + ks) * 4 + ahalf) * 96 + (lane & 15);
            a0 = MFMA16(af[ks], bp[0],  a0);
            a1 = MFMA16(af[ks], bp[16], a1);
            a2 = MFMA16(af[ks], bp[32], a2);
            a3 = MFMA16(af[ks], bp[48], a3);
            a4 = MFMA16(af[ks], bp[64], a4);
            a5 = MFMA16(af[ks], bp[80], a5);
        }
        a0  = MFMA16(xa, bxr[0], a0);
        a1  = MFMA16(xa, bxr[1], a1);
        a2  = MFMA16(xa, bxr[2], a2);
        a3  = MFMA16(xa, bxr[3], a3);
        ax0 = MFMA16(xa, bxr[4], ax0);
        ax1 = MFMA16(xa, bxr[5], ax1);

        // ---- stash 8 tiles of partials ----
        {
            float* rb = red + wave * 2048;
            #pragma unroll
            for (int i = 0; i < 4; ++i) {
                int rix = (ahalf * 4 + i) * 16 + (lane & 15);
                rb[           rix] = a0[i];
                rb[1 * 256 + rix] = a1[i];
                rb[2 * 256 + rix] = a2[i];
                rb[3 * 256 + rix] = a3[i];
                rb[4 * 256 + rix] = a4[i];
                rb[5 * 256 + rix] = a5[i];
                rb[6 * 256 + rix] = ax0[i];
                rb[7 * 256 + rix] = ax1[i];
            }
        }
        barrier_lgkm();

        // ---- gates: 2 cols per thread; pack 2xf16 -> one 4B coherent store ----
        unsigned pack = 0;
        #pragma unroll
        for (int s = 0; s < 2; ++s) {
            int clocal = cp * 2 + s;
            int hb2 = clocal >> 4, base = brow * 16 + (clocal & 15);
            float zp = red[(0+hb2)*256+base] + red[2048+(0+hb2)*256+base]
                     + red[4096+(0+hb2)*256+base] + red[6144+(0+hb2)*256+base];
            float rp = red[(2+hb2)*256+base] + red[2048+(2+hb2)*256+base]
                     + red[4096+(2+hb2)*256+base] + red[6144+(2+hb2)*256+base];
            float hp = red[(4+hb2)*256+base] + red[2048+(4+hb2)*256+base]
                     + red[4096+(4+hb2)*256+base] + red[6144+(4+hb2)*256+base];
            float xh = red[(6+hb2)*256+base] + red[2048+(6+hb2)*256+base]
                     + red[4096+(6+hb2)*256+base] + red[6144+(6+hb2)*256+base];
            float z = sigmoid_f(zp + bZs[s]);
            float r = sigmoid_f(rp + bRs[s]);
            float hc = tanh_f((xh + bXs[s]) + r * (hp + bHs[s]));
            float hn = z * hold[s] + (1.f - z) * hc;
            f16 h16 = (f16)hn;
            hold[s] = (float)h16;
            union { f16 h; unsigned short u; } cv; cv.h = h16;
            pack |= ((unsigned)cv.u) << (16 * s);
        }
        st_u32c(hring + ((size_t)(cur ^ 1) * NG + g) * MB * HID
                      + (size_t)brow * HID + j0 + cp * 2, pack);
        WAITV0;            // own wave's h-store at coherence point
        barrier_lgkm();    // all 4 waves drained; red reuse safe
        if (tid == 0) st_u32c(myflag, (unsigned)(t + 1));
    }

    // ---- final poll: all 16 flags >= SEQL ----
    {
        const unsigned* fh = flg + g * WPG + (lane & 15);
        for (;;) {
            unsigned v;
            asm volatile("global_load_dword %0, %1, off sc0 sc1" : "=v"(v) : "v"(fh) : "memory");
            asm volatile("s_waitcnt vmcnt(0)" ::: "memory");
            __builtin_amdgcn_sched_barrier(0);
            if (__all((int)(v >= (unsigned)SEQL))) break;
        }
    }
    __syncthreads();

    // ---- head: thread (r=tid>>4, kq=tid&15); WG owns DENSE1 cols wgk*4..+4 ----
    {
        const int r = tid >> 4, kq = tid & 15;
        const int c0 = wgk * 4;
        const f16* hf = hring + ((size_t)g * MB + r) * HID;   // slot 0 = h_512
        float p[4] = {0,0,0,0}, wsu[4] = {0,0,0,0};
        for (int q = 0; q < 8; ++q) {
            union { unsigned long long u; f16 h[4]; } x;
            x.u = ld_u64c(hf + kq * 32 + q * 4);
            #pragma unroll
            for (int e = 0; e < 4; ++e) {
                int k = kq * 32 + q * 4 + e;
                float hv = (float)x.h[e];
                #pragma unroll
                for (int cc = 0; cc < 4; ++cc) {
                    float w = W1[(size_t)k * DEN1 + c0 + cc];
                    p[cc] += hv * w; wsu[cc] += w;
                }
            }
        }
        #pragma unroll
        for (int cc = 0; cc < 4; ++cc) {
            red[cc * 256 + r * 16 + kq] = p[cc];
            red[1024 + cc * 256 + r * 16 + kq] = wsu[cc];
        }
    }
    __syncthreads();
    if (tid < 64) {
        int r = tid >> 2, cc = tid & 3;
        int c = wgk * 4 + cc;
        float dot = 0.f, ws2 = 0.f;
        for (int i = 0; i < 16; ++i) {
            dot += red[cc * 256 + r * 16 + i];
            ws2 += red[1024 + cc * 256 + r * 16 + i];
        }
        union { unsigned u; float f; } sm; sm.u = ld_u32c(smw + g * MB + r);
        float d = dot + sm.f * Wsh[0] * ws2 + b1[c];
        d = fmaxf(d, 0.f);
        d = (d - mmn[c]) * rsqrtf(mvr[c] + 0.001f) * gam[c] + bet[c];
        red[2048 + tid] = d * W2[c];
    }
    __syncthreads();
    if (tid < MB) {
        float v = red[2048 + tid * 4] + red[2048 + tid * 4 + 1]
                + red[2048 + tid * 4 + 2] + red[2048 + tid * 4 + 3];
        union { float f; unsigned u; } cv; cv.f = v;
        st_u32c(hpart + ((size_t)g * WPG + wgk) * MB + tid, cv.u);
    }
    WAITV0;
    __syncthreads();
    if (tid == 0) {
        __builtin_amdgcn_fence(__ATOMIC_RELEASE, "agent");
        unsigned* c9 = ctr + g;
        unsigned old = __hip_atomic_fetch_add(c9, 1u, __ATOMIC_RELAXED, __HIP_MEMORY_SCOPE_AGENT);
        if (old != WPG - 1)
            while (__hip_atomic_load(c9, __ATOMIC_RELAXED, __HIP_MEMORY_SCOPE_AGENT) < WPG) {}
        __builtin_amdgcn_fence(__ATOMIC_ACQUIRE, "agent");
    }
    __syncthreads();
    if (wgk == 0 && tid < MB) {
        float o = b2p[0];
        for (int k = 0; k < WPG; ++k) {       // fixed order -> deterministic
            union { unsigned u; float f; } hv;
            hv.u = ld_u32c(hpart + ((size_t)g * WPG + k) * MB + tid);
            o += hv.f;
        }
        out[g * MB + tid] = o;
    }
}

extern "C" void kernel_launch(void* const* d_in, const int* in_sizes, int n_in,
                              void* d_out, int out_size, void* d_ws, size_t ws_size,
                              hipStream_t stream) {
    (void)in_sizes; (void)n_in; (void)out_size; (void)ws_size;
    const float* inp  = (const float*)d_in[0];
    const float* Wk   = (const float*)d_in[1];
    const float* Rk   = (const float*)d_in[2];
    const float* bias = (const float*)d_in[3];
    const float* W1   = (const float*)d_in[4];
    const float* b1   = (const float*)d_in[5];
    const float* gam  = (const float*)d_in[6];
    const float* bet  = (const float*)d_in[7];
    const float* mmn  = (const float*)d_in[8];
    const float* mvr  = (const float*)d_in[9];
    const float* W2   = (const float*)d_in[10];
    const float* b2p  = (const float*)d_in[11];
    const float* Wsh  = (const float*)d_in[12];

    hipMemsetAsync(d_ws, 0, WS_END, stream);   // flags/counters + h0 = 0, every launch
    hipLaunchKernelGGL(gru_fused, dim3(NG * WPG), dim3(THREADS), 0, stream,
                       inp, Wk, Rk, bias, W1, b1, gam, bet, mmn, mvr, W2, b2p, Wsh,
                       (float*)d_out, (char*)d_ws);
}

// Round 11
// 1472.591 us; speedup vs baseline: 2.7217x; 1.1514x over previous
//
#include <hip/hip_runtime.h>
#include <hip/hip_fp16.h>

typedef _Float16 f16;
typedef _Float16 f16x8 __attribute__((ext_vector_type(8)));
typedef float    f32x4 __attribute__((ext_vector_type(4)));
typedef unsigned int u32x4 __attribute__((ext_vector_type(4)));

#define HID 512
#define FEA 128
#define ROWSTR 129            // inputs row = 128 feat + 1 shock
#define SEQL 512
#define DEN1 64
#define NG 8                  // batch groups (16 rows each)
#define WPG 32                // workgroups per group
#define MB 16                 // batch rows per group
#define GC 16                 // gate columns per wg
#define THREADS 256

// workspace (bytes); zeroed every launch via hipMemsetAsync
#define WS_CTR    0                     // 64 u32: final-barrier counters
#define WS_HT     4096                  // 2*NG*MB*HID u32 tagged h = 524288 B
#define WS_SM     (WS_HT + 524288)      // 128 f32 shock means
#define WS_HPART  (WS_SM + 1024)        // NG*WPG*MB f32 head partials
#define WS_END    (WS_HPART + 16384)

#define WAITV0 { asm volatile("s_waitcnt vmcnt(0)" ::: "memory"); __builtin_amdgcn_sched_barrier(0); }

__device__ __forceinline__ void st_u32c(void* p, unsigned v) {
    asm volatile("global_store_dword %0, %1, off sc0 sc1" :: "v"(p), "v"(v) : "memory");
}
__device__ __forceinline__ unsigned ld_u32c(const void* p) {
    unsigned r;
    asm volatile("global_load_dword %0, %1, off sc0 sc1" : "=v"(r) : "v"(p) : "memory");
    asm volatile("s_waitcnt vmcnt(0)" ::: "memory");
    return r;
}
__device__ __forceinline__ void barrier_lgkm() {
    asm volatile("s_waitcnt lgkmcnt(0)" ::: "memory");
    __builtin_amdgcn_sched_barrier(0);
    __builtin_amdgcn_s_barrier();
    __builtin_amdgcn_sched_barrier(0);
    asm volatile("" ::: "memory");
}
// unpack 8 tagged u32 -> f16x8 (low halves)
__device__ __forceinline__ f16x8 unpack8(u32x4 a, u32x4 b) {
    union { unsigned u[4]; f16x8 v; } r;
    r.u[0] = (a[0] & 0xffffu) | (a[1] << 16);
    r.u[1] = (a[2] & 0xffffu) | (a[3] << 16);
    r.u[2] = (b[0] & 0xffffu) | (b[1] << 16);
    r.u[3] = (b[2] & 0xffffu) | (b[3] << 16);
    return r.v;
}
__device__ __forceinline__ int tagok(u32x4 a, unsigned wt) {
    return (a[0] >> 16) == wt && (a[1] >> 16) == wt &&
           (a[2] >> 16) == wt && (a[3] >> 16) == wt;
}

__device__ __forceinline__ float sigmoid_f(float x) {
    x = fminf(fmaxf(x, -30.f), 30.f);
    return 1.f / (1.f + __expf(-x));
}
__device__ __forceinline__ float tanh_f(float x) {
    x = fminf(fmaxf(x, -15.f), 15.f);
    float e = __expf(2.f * x);
    return (e - 1.f) / (e + 1.f);
}

__global__ __launch_bounds__(THREADS)
void gru_fused(const float* __restrict__ inp, const float* __restrict__ Wk,
               const float* __restrict__ Rk,  const float* __restrict__ bias,
               const float* __restrict__ W1,  const float* __restrict__ b1,
               const float* __restrict__ gam, const float* __restrict__ bet,
               const float* __restrict__ mmn, const float* __restrict__ mvr,
               const float* __restrict__ W2,  const float* __restrict__ b2p,
               const float* __restrict__ Wsh, float* __restrict__ out,
               char* __restrict__ ws)
{
    __shared__ __align__(16) f16 Bh[512 * 48];   // 49152 B: R gate-col B-frags
    __shared__ __align__(16) f16 Bx[128 * 48];   // 12288 B: Wk gate-col B-frags
    __shared__ float red[4608];                   // 18432 B
    // LDS 79872 B -> 2 blocks/CU capacity (R1-R3 proven regime)

    const int tid  = threadIdx.x;
    const int g    = blockIdx.x & (NG - 1);
    const int wgk  = blockIdx.x >> 3;
    const int lane = tid & 63;
    const int wave = tid >> 6;
    const int j0   = wgk * GC;

    unsigned* ctr   = (unsigned*)(ws + WS_CTR);
    unsigned* hT    = (unsigned*)(ws + WS_HT);     // tagged h: (tag<<16)|f16bits
    float*    smw   = (float*)(ws + WS_SM);
    float*    hpart = (float*)(ws + WS_HPART);

    // ---- stage B-fragments ----
    for (int idx = tid; idx < 512 * 48; idx += THREADS) {
        int kk = idx / 48, c = idx - kk * 48;
        int col = (c >> 4) * HID + j0 + (c & 15);
        Bh[((kk >> 3) * 48 + c) * 8 + (kk & 7)] = (f16)Rk[(size_t)kk * 1536 + col];
    }
    for (int idx = tid; idx < 128 * 48; idx += THREADS) {
        int kk = idx / 48, c = idx - kk * 48;
        int col = (c >> 4) * HID + j0 + (c & 15);
        Bx[((kk >> 3) * 48 + c) * 8 + (kk & 7)] = (f16)Wk[(size_t)kk * 1536 + col];
    }

    // ---- shock mean (coherent publish) ----
    if (wgk < MB) {
        int b = g * MB + wgk;
        float a = 0.f;
        for (int t = tid; t < SEQL; t += THREADS)
            a += inp[((size_t)b * SEQL + t) * ROWSTR + FEA];
        red[tid] = a;
        __syncthreads();
        for (int s = THREADS / 2; s > 0; s >>= 1) {
            if (tid < s) red[tid] += red[tid + s];
            __syncthreads();
        }
        if (tid == 0) {
            union { float f; unsigned u; } cv; cv.f = red[0] * (1.f / SEQL);
            st_u32c(smw + b, cv.u);
        }
    }

    // per-thread constants
    const int brow  = tid >> 4;
    const int jcol  = j0 + (tid & 15);
    const int arow  = lane & 15;
    const int ahalf = lane >> 4;
    const int lcol  = j0 + (lane & 15);
    const float bZ3  = bias[lcol] + bias[1536 + lcol];
    const float bR3  = bias[512 + lcol] + bias[1536 + 512 + lcol];
    const float bX3  = bias[1024 + lcol];
    const float bHH3 = bias[1536 + 1024 + lcol];

    float xa[4][8];   // wave3: x floats, ~2 steps ahead

    auto x_window = [&](int t) {   // convert x(t+1), 12 MFMAs, stash, load x(t+2)
        f16x8 afx[4];
        #pragma unroll
        for (int s = 0; s < 4; ++s) {
            f16x8 a;
            #pragma unroll
            for (int q = 0; q < 8; ++q) a[q] = (f16)xa[s][q];
            afx[s] = a;
        }
        f32x4 az = {0,0,0,0}, ar = {0,0,0,0}, ah = {0,0,0,0};
        #pragma unroll
        for (int s = 0; s < 4; ++s) {
            const f16x8* bx = ((const f16x8*)Bx) + (s * 4 + ahalf) * 48 + (lane & 15);
            az = __builtin_amdgcn_mfma_f32_16x16x32_f16(afx[s], bx[0],  az, 0, 0, 0);
            ar = __builtin_amdgcn_mfma_f32_16x16x32_f16(afx[s], bx[16], ar, 0, 0, 0);
            ah = __builtin_amdgcn_mfma_f32_16x16x32_f16(afx[s], bx[32], ah, 0, 0, 0);
        }
        float* xo = red + 3072 + ((t + 1) & 1) * 768;
        #pragma unroll
        for (int i = 0; i < 4; ++i) {
            int rix = (ahalf * 4 + i) * 16 + (lane & 15);
            xo[rix]       = az[i] + bZ3;
            xo[256 + rix] = ar[i] + bR3;
            xo[512 + rix] = ah[i] + bX3;
        }
        int tt = (t + 2 < SEQL) ? t + 2 : SEQL - 1;
        const float* xs = inp + ((size_t)(g * MB + arow) * SEQL + tt) * ROWSTR + ahalf * 8;
        #pragma unroll
        for (int s = 0; s < 4; ++s)
            #pragma unroll
            for (int q = 0; q < 8; ++q)
                xa[s][q] = xs[s * 32 + q];
    };

    __syncthreads();   // staging + shock-mean done

    if (wave == 3) {   // prologue: stash x-proj(0), issue x(1)
        const float* xs = inp + ((size_t)(g * MB + arow) * SEQL + 0) * ROWSTR + ahalf * 8;
        #pragma unroll
        for (int s = 0; s < 4; ++s)
            #pragma unroll
            for (int q = 0; q < 8; ++q)
                xa[s][q] = xs[s * 32 + q];
        x_window(-1);
    }

    float hold = 0.f;  // own h element (h0 = 0; memset gives tag 0 == want at t=0)

    #pragma unroll 1
    for (int t = 0; t < SEQL; ++t) {
        const int cur = t & 1;
        const unsigned want = (unsigned)t;

        // ---- tagged poll+load: the h data IS the flag ----
        f16x8 af[5];
        if (wave < 3) {
            const unsigned* hb = hT + ((size_t)cur * NG + g) * MB * HID
                                    + (size_t)arow * HID + wave * 5 * 32 + ahalf * 8;
            u32x4 ta[10];
            for (;;) {
                #pragma unroll
                for (int s = 0; s < 5; ++s) {
                    asm volatile("global_load_dwordx4 %0, %1, off offset:%c2 sc0 sc1"
                                 : "=v"(ta[2*s])   : "v"(hb), "i"(s * 128));
                    asm volatile("global_load_dwordx4 %0, %1, off offset:%c2 sc0 sc1"
                                 : "=v"(ta[2*s+1]) : "v"(hb), "i"(s * 128 + 16));
                }
                WAITV0;
                int ok = 1;
                #pragma unroll
                for (int j = 0; j < 10; ++j) ok &= tagok(ta[j], want);
                if (__all(ok)) break;
            }
            #pragma unroll
            for (int s = 0; s < 5; ++s) af[s] = unpack8(ta[2*s], ta[2*s+1]);
        } else {
            const unsigned* hb = hT + ((size_t)cur * NG + g) * MB * HID
                                    + (size_t)arow * HID + 15 * 32 + ahalf * 8;
            u32x4 t0, t1;
            for (;;) {
                asm volatile("global_load_dwordx4 %0, %1, off sc0 sc1"           : "=v"(t0) : "v"(hb));
                asm volatile("global_load_dwordx4 %0, %1, off offset:16 sc0 sc1" : "=v"(t1) : "v"(hb));
                WAITV0;
                if (__all(tagok(t0, want) && tagok(t1, want))) break;
            }
            af[0] = unpack8(t0, t1);
        }

        // ---- MFMA partials (identical to R3) ----
        f32x4 aZ = {0,0,0,0}, aR = {0,0,0,0}, aH = {0,0,0,0};
        if (wave < 3) {
            #pragma unroll
            for (int s = 0; s < 5; ++s) {
                int ks = wave * 5 + s;
                const f16x8* bp = ((const f16x8*)Bh) + (ks * 4 + ahalf) * 48 + (lane & 15);
                aZ = __builtin_amdgcn_mfma_f32_16x16x32_f16(af[s], bp[0],  aZ, 0, 0, 0);
                aR = __builtin_amdgcn_mfma_f32_16x16x32_f16(af[s], bp[16], aR, 0, 0, 0);
                aH = __builtin_amdgcn_mfma_f32_16x16x32_f16(af[s], bp[32], aH, 0, 0, 0);
            }
            #pragma unroll
            for (int i = 0; i < 4; ++i) {
                int rix = (ahalf * 4 + i) * 16 + (lane & 15);
                red[wave * 768 +       rix] = aZ[i];
                red[wave * 768 + 256 + rix] = aR[i];
                red[wave * 768 + 512 + rix] = aH[i];
            }
        } else {
            const f16x8* bp = ((const f16x8*)Bh) + (15 * 4 + ahalf) * 48 + (lane & 15);
            aZ = __builtin_amdgcn_mfma_f32_16x16x32_f16(af[0], bp[0],  aZ, 0, 0, 0);
            aR = __builtin_amdgcn_mfma_f32_16x16x32_f16(af[0], bp[16], aR, 0, 0, 0);
            aH = __builtin_amdgcn_mfma_f32_16x16x32_f16(af[0], bp[32], aH, 0, 0, 0);
            #pragma unroll
            for (int i = 0; i < 4; ++i) {
                int rix = (ahalf * 4 + i) * 16 + (lane & 15);
                red[3 * 768 +       rix] = aZ[i];
                red[3 * 768 + 256 + rix] = aR[i];
                red[3 * 768 + 512 + rix] = aH[i] + bHH3;
            }
        }
        barrier_lgkm();   // partials + x-stash visible

        // ---- gates: thread owns (brow, jcol); tagged store, NO drain, NO flag ----
        {
            float zp = red[tid] + red[768 + tid] + red[1536 + tid] + red[2304 + tid];
            float rp = red[256 + tid] + red[1024 + tid] + red[1792 + tid] + red[2560 + tid];
            float hp = red[512 + tid] + red[1280 + tid] + red[2048 + tid] + red[2816 + tid];
            const float* xi = red + 3072 + cur * 768;
            float z = sigmoid_f(zp + xi[tid]);
            float r = sigmoid_f(rp + xi[256 + tid]);
            float hc = tanh_f(xi[512 + tid] + r * hp);
            float hnew = z * hold + (1.f - z) * hc;
            f16 h16 = (f16)hnew;
            hold = (float)h16;
            union { f16 h; unsigned short u; } cv; cv.h = h16;
            st_u32c(hT + ((size_t)(cur ^ 1) * NG + g) * MB * HID
                       + (size_t)brow * HID + jcol,
                    (unsigned)cv.u | ((unsigned)(t + 1) << 16));
        }

        if (wave == 3 && t + 1 < SEQL)
            x_window(t);     // x(t+2) loads left in flight; next poll drains them

        barrier_lgkm();      // red/x-stash reuse safe
    }

    __syncthreads();

    // ---- head: tagged poll-read of h_512 (slot 0, tag == SEQL) ----
    const unsigned* hf = hT + ((size_t)g * MB + brow) * HID + (tid & 15) * 32;
    const int c0 = wgk * 2;
    u32x4 hv[8];
    for (;;) {
        #pragma unroll
        for (int c8 = 0; c8 < 8; ++c8)
            asm volatile("global_load_dwordx4 %0, %1, off offset:%c2 sc0 sc1"
                         : "=v"(hv[c8]) : "v"(hf), "i"(c8 * 16));
        WAITV0;
        int ok = 1;
        #pragma unroll
        for (int c8 = 0; c8 < 8; ++c8) ok &= tagok(hv[c8], (unsigned)SEQL);
        if (__all(ok)) break;
    }
    float p0 = 0.f, p1 = 0.f, w0 = 0.f, w1 = 0.f;
    for (int c8 = 0; c8 < 8; ++c8) {
        #pragma unroll
        for (int e = 0; e < 4; ++e) {
            int k = (tid & 15) * 32 + c8 * 4 + e;
            union { unsigned short s; f16 h; } cc;
            cc.s = (unsigned short)(hv[c8][e] & 0xffffu);
            float hvv = (float)cc.h;
            float a0 = W1[(size_t)k * DEN1 + c0];
            float a1 = W1[(size_t)k * DEN1 + c0 + 1];
            p0 += hvv * a0; p1 += hvv * a1; w0 += a0; w1 += a1;
        }
    }
    __syncthreads();
    red[tid] = p0; red[256 + tid] = w0; red[512 + tid] = p1; red[768 + tid] = w1;
    __syncthreads();
    if (tid < 32) {
        int b = tid >> 1, cc = tid & 1;
        int c = c0 + cc;
        float dot = 0.f, wsum = 0.f;
        for (int i = 0; i < 16; ++i) {
            dot  += red[cc * 512 + b * 16 + i];
            wsum += red[cc * 512 + 256 + b * 16 + i];
        }
        union { unsigned u; float f; } sm; sm.u = ld_u32c(smw + g * MB + b);
        float sW = sm.f * Wsh[0];
        float d = dot + sW * wsum + b1[c];
        d = fmaxf(d, 0.f);
        d = (d - mmn[c]) * rsqrtf(mvr[c] + 0.001f) * gam[c] + bet[c];
        red[1024 + tid] = d * W2[c];
    }
    __syncthreads();
    if (tid < MB)
        hpart[((size_t)g * WPG + wgk) * MB + tid] = red[1024 + tid * 2] + red[1024 + tid * 2 + 1];
    __syncthreads();
    if (tid == 0) {
        __builtin_amdgcn_fence(__ATOMIC_RELEASE, "agent");
        unsigned* c9 = ctr + g;
        unsigned old = __hip_atomic_fetch_add(c9, 1u, __ATOMIC_RELAXED, __HIP_MEMORY_SCOPE_AGENT);
        if (old != WPG - 1)
            while (__hip_atomic_load(c9, __ATOMIC_RELAXED, __HIP_MEMORY_SCOPE_AGENT) < WPG) {}
        __builtin_amdgcn_fence(__ATOMIC_ACQUIRE, "agent");
    }
    __syncthreads();
    if (wgk == 0 && tid < MB) {
        float o = b2p[0];
        for (int k = 0; k < WPG; ++k)
            o += hpart[((size_t)g * WPG + k) * MB + tid];
        out[g * MB + tid] = o;
    }
}

extern "C" void kernel_launch(void* const* d_in, const int* in_sizes, int n_in,
                              void* d_out, int out_size, void* d_ws, size_t ws_size,
                              hipStream_t stream) {
    (void)in_sizes; (void)n_in; (void)out_size; (void)ws_size;
    const float* inp  = (const float*)d_in[0];
    const float* Wk   = (const float*)d_in[1];
    const float* Rk   = (const float*)d_in[2];
    const float* bias = (const float*)d_in[3];
    const float* W1   = (const float*)d_in[4];
    const float* b1   = (const float*)d_in[5];
    const float* gam  = (const float*)d_in[6];
    const float* bet  = (const float*)d_in[7];
    const float* mmn  = (const float*)d_in[8];
    const float* mvr  = (const float*)d_in[9];
    const float* W2   = (const float*)d_in[10];
    const float* b2p  = (const float*)d_in[11];
    const float* Wsh  = (const float*)d_in[12];

    hipMemsetAsync(d_ws, 0, WS_END, stream);   // tags=0 (== want at t=0), h0=0, ctr=0
    hipLaunchKernelGGL(gru_fused, dim3(NG * WPG), dim3(THREADS), 0, stream,
                       inp, Wk, Rk, bias, W1, b1, gam, bet, mmn, mvr, W2, b2p, Wsh,
                       (float*)d_out, (char*)d_ws);
}